// Round 6
// baseline (2513.928 us; speedup 1.0000x reference)
//
#include <hip/hip_runtime.h>
#include <hip/hip_bf16.h>

#define B 64
#define KDIM 196
#define H 512
#define V 10000
#define TSTEPS 30
#define VP 10240    // padded V for fcT / base
#define NVC 40      // VP/256 chunks for base finish
#define NSLOT 8     // argmax atomic contention-spread slots per b
#define SLOTSTRIDE 16  // u64 stride per b -> 128B, own cache line

typedef unsigned long long u64;
typedef unsigned int u32;

// pack (value, index) into sortable u64: bigger = (bigger value, then smaller index)
__device__ __forceinline__ u64 pack_vi(float v, int idx) {
    u32 kb = __float_as_uint(v);
    kb = (kb & 0x80000000u) ? ~kb : (kb | 0x80000000u);
    return ((u64)kb << 32) | (u32)(~(u32)idx);
}
__device__ __forceinline__ u32 best_idx_of_slots(const u64* __restrict__ slots, int b) {
    u64 best = slots[b * SLOTSTRIDE];
#pragma unroll
    for (int s = 1; s < NSLOT; ++s) { u64 v = slots[b * SLOTSTRIDE + s]; if (v > best) best = v; }
    return ~(u32)best;
}

// ---------------- precompute kernels ----------------

// dst[i][v] = fc_w[v][coloff + i], i in [0,512), v in [0,VP) (zero-padded)
__global__ void k_transpose_fc(const float* __restrict__ fcw, float* __restrict__ dst, int coloff) {
    __shared__ float tile[32][33];
    int v0 = blockIdx.x * 32, i0 = blockIdx.y * 32;
    int tx = threadIdx.x, ty = threadIdx.y;
#pragma unroll
    for (int r = 0; r < 32; r += 8) {
        int v = v0 + ty + r; int i = i0 + tx;
        tile[ty + r][tx] = (v < V) ? fcw[(size_t)v * 1024 + coloff + i] : 0.f;
    }
    __syncthreads();
#pragma unroll
    for (int r = 0; r < 32; r += 8) {
        int i = i0 + ty + r; int v = v0 + tx;
        dst[(size_t)i * VP + v] = tile[tx][ty + r];
    }
}

// WcT[i][j] = (i<512) ? wih[j][i] : whh[j][i-512];  i<1024, j<2048
__global__ void k_build_wct(const float* __restrict__ wih, const float* __restrict__ whh,
                            float* __restrict__ dst) {
    __shared__ float tile[32][33];
    int j0 = blockIdx.x * 32, i0 = blockIdx.y * 32;
    int tx = threadIdx.x, ty = threadIdx.y;
#pragma unroll
    for (int r = 0; r < 32; r += 8) {
        int j = j0 + ty + r; int i = i0 + tx;
        tile[ty + r][tx] = (i < 512) ? wih[(size_t)j * 512 + i] : whh[(size_t)j * 512 + i - 512];
    }
    __syncthreads();
#pragma unroll
    for (int r = 0; r < 32; r += 8) {
        int i = i0 + ty + r; int j = j0 + tx;
        dst[(size_t)i * 2048 + j] = tile[tx][ty + r];
    }
}

// mean over K per (b,h) row; one wave per row
__global__ void k_mean(const float* __restrict__ iml, float* __restrict__ mean) {
    int w = threadIdx.x >> 6, lane = threadIdx.x & 63;
    int row = blockIdx.x * 4 + w;
    const float* p = iml + (size_t)row * KDIM;
    float s = p[lane] + p[lane + 64] + p[lane + 128] + ((lane < 4) ? p[lane + 192] : 0.f);
#pragma unroll
    for (int off = 32; off; off >>= 1) s += __shfl_down(s, off);
    if (lane == 0) mean[row] = s * (1.f / 196.f);
}

// alpha[b][k] = softmax_k( sum_h iml[b][h][k] * attn_w[h] )
__global__ void k_e_alpha(const float* __restrict__ iml, const float* __restrict__ attn_w,
                          float* __restrict__ alpha) {
    int b = blockIdx.x, t = threadIdx.x;
    __shared__ float wa[512];
    wa[t] = attn_w[t]; wa[t + 256] = attn_w[t + 256];
    __syncthreads();
    float acc = 0.f;
    if (t < KDIM) {
        const float* p = iml + (size_t)b * 512 * KDIM + t;
#pragma unroll 8
        for (int h = 0; h < 512; ++h) acc += p[(size_t)h * KDIM] * wa[h];
    }
    __shared__ float red[256];
    red[t] = (t < KDIM) ? acc : -__builtin_inff();
    __syncthreads();
    for (int s = 128; s; s >>= 1) { if (t < s) red[t] = fmaxf(red[t], red[t + s]); __syncthreads(); }
    float mx = red[0];
    __syncthreads();
    float ex = (t < KDIM) ? expf(acc - mx) : 0.f;
    red[t] = ex; __syncthreads();
    for (int s = 128; s; s >>= 1) { if (t < s) red[t] += red[t + s]; __syncthreads(); }
    if (t < KDIM) alpha[b * KDIM + t] = ex / red[0];
}

// cs[b][h] = sum_k alpha[b][k] * iml[b][h][k]; one wave per row
__global__ void k_cs(const float* __restrict__ iml, const float* __restrict__ alpha,
                     float* __restrict__ cs) {
    int w = threadIdx.x >> 6, lane = threadIdx.x & 63;
    int row = blockIdx.x * 4 + w;
    int b = row >> 9;
    const float* p = iml + (size_t)row * KDIM;
    const float* al = alpha + b * KDIM;
    float s = p[lane] * al[lane] + p[lane + 64] * al[lane + 64] + p[lane + 128] * al[lane + 128]
            + ((lane < 4) ? p[lane + 192] * al[lane + 192] : 0.f);
#pragma unroll
    for (int off = 32; off; off >>= 1) s += __shfl_down(s, off);
    if (lane == 0) cs[row] = s;
}

// out[b*ostride + j] = relu(bias[j] + sum_i in[b][i] * W[j][i])
__global__ void k_dense_relu(const float* __restrict__ in, const float* __restrict__ W,
                             const float* __restrict__ bias, float* __restrict__ out, int ostride) {
    int b = blockIdx.y; int j = blockIdx.x * 256 + threadIdx.x;
    __shared__ float xs[512];
    xs[threadIdx.x] = in[b * 512 + threadIdx.x];
    xs[threadIdx.x + 256] = in[b * 512 + threadIdx.x + 256];
    __syncthreads();
    float acc = bias[j];
    const float4* w4 = (const float4*)(W + (size_t)j * 512);
#pragma unroll 4
    for (int i4 = 0; i4 < 128; ++i4) {
        float4 w = w4[i4];
        float4 x = *(const float4*)&xs[i4 * 4];
        acc += w.x * x.x + w.y * x.y + w.z * x.z + w.w * x.w;
    }
    out[(size_t)b * ostride + j] = fmaxf(acc, 0.f);
}

// split-K GEMM for the one-time base-logits (cs @ fcT_hi)
__global__ void k_gemm_big(const float* __restrict__ A, int astride,
                           const float* __restrict__ Wt, int wn,
                           float* __restrict__ part) {
    int jb = blockIdx.x, kc = blockIdx.y, bh = blockIdx.z;
    int w = threadIdx.x >> 6, lane = threadIdx.x & 63;
    int b0 = __builtin_amdgcn_readfirstlane(bh * 32 + w * 8);
    int k0 = kc * 64;
    int j0 = jb * 256 + lane * 4;
    float4 acc[8];
#pragma unroll
    for (int b = 0; b < 8; ++b) acc[b] = make_float4(0.f, 0.f, 0.f, 0.f);
    const float* wp = Wt + (size_t)k0 * wn + j0;
    const float* xp = A + (size_t)b0 * astride + k0;
#pragma unroll 8
    for (int kk = 0; kk < 64; ++kk) {
        float4 w4 = *(const float4*)(wp + (size_t)kk * wn);
#pragma unroll
        for (int b = 0; b < 8; ++b) {
            float xv = xp[(size_t)b * astride + kk];
            acc[b].x += xv * w4.x; acc[b].y += xv * w4.y;
            acc[b].z += xv * w4.z; acc[b].w += xv * w4.w;
        }
    }
#pragma unroll
    for (int b = 0; b < 8; ++b)
        *(float4*)(part + (size_t)(kc * 64 + b0 + b) * wn + j0) = acc[b];
}

// base[b][v] = sum of 8 partials + fc_b[v]; block(0,0) also zeroes argmax slots
__global__ void k_base_finish(const float* __restrict__ lpart, const float* __restrict__ fc_b,
                              float* __restrict__ base, u64* __restrict__ slots) {
    int b = blockIdx.y; int v = blockIdx.x * 256 + threadIdx.x;
    if (v < V) {
        float s = fc_b[v];
#pragma unroll
        for (int c = 0; c < 8; ++c) s += lpart[(size_t)(c * 64 + b) * VP + v];
        base[(size_t)b * VP + v] = s;
    }
    if (blockIdx.x == 0 && blockIdx.y == 0) {
#pragma unroll
        for (int i = 0; i < 4; ++i) slots[threadIdx.x + i * 256] = 0ull;   // 64*16 u64
    }
}

// ---------------- per-step kernels ----------------

// LSTM gates GEMM, split-K 16. x = t0 ? img : emb[argmax(slots)]; h from hbuf.
// grid (8, 16, 2), 256 thr. part[(kc*64+b)*2048 + j]
__global__ void k_lstm_gemm(const float* __restrict__ img, const float* __restrict__ emb,
                            const u64* __restrict__ slots, const float* __restrict__ hbuf,
                            const float* __restrict__ WcT, float* __restrict__ part, int t0) {
    int jb = blockIdx.x, kc = blockIdx.y, bh = blockIdx.z;
    int w = threadIdx.x >> 6, lane = threadIdx.x & 63;
    int b0 = __builtin_amdgcn_readfirstlane(bh * 32 + w * 8);
    int k0 = kc * 64;
    int j0 = jb * 256 + lane * 4;
    const float* xr[8];
    if (k0 < 512) {
        if (t0) {
#pragma unroll
            for (int i = 0; i < 8; ++i) xr[i] = img + (size_t)(b0 + i) * 512 + k0;
        } else {
#pragma unroll
            for (int i = 0; i < 8; ++i) {
                u32 idx = best_idx_of_slots(slots, b0 + i);
                xr[i] = emb + (size_t)idx * 512 + k0;
            }
        }
    } else {
#pragma unroll
        for (int i = 0; i < 8; ++i) xr[i] = hbuf + (size_t)(b0 + i) * 512 + (k0 - 512);
    }
    float4 acc[8];
#pragma unroll
    for (int b = 0; b < 8; ++b) acc[b] = make_float4(0.f, 0.f, 0.f, 0.f);
    const float* wp = WcT + (size_t)k0 * 2048 + j0;
#pragma unroll 8
    for (int kk = 0; kk < 64; ++kk) {
        float4 w4 = *(const float4*)(wp + (size_t)kk * 2048);
#pragma unroll
        for (int i = 0; i < 8; ++i) {
            float xv = xr[i][kk];
            acc[i].x += xv * w4.x; acc[i].y += xv * w4.y;
            acc[i].z += xv * w4.z; acc[i].w += xv * w4.w;
        }
    }
#pragma unroll
    for (int i = 0; i < 8; ++i)
        *(float4*)(part + (size_t)(kc * 64 + b0 + i) * 2048 + j0) = acc[i];
}

// reduce 16 partials + biases + gates; h -> hbuf, c in place.
// block 0 additionally: out1[b][t-1] from slots, then zero slots.
__global__ void k_gates(const float* __restrict__ part, const float* __restrict__ bih,
                        const float* __restrict__ bhh, float* __restrict__ hbuf,
                        float* __restrict__ cbuf, u64* __restrict__ slots,
                        float* __restrict__ out1, int t) {
    int e = blockIdx.x * 256 + threadIdx.x;
    int b = e >> 9, jj = e & 511;
    float g[4];
#pragma unroll
    for (int gg = 0; gg < 4; ++gg) {
        int j = jj + gg * 512;
        float s = bih[j] + bhh[j];
#pragma unroll
        for (int c = 0; c < 16; ++c) s += part[(size_t)(c * 64 + b) * 2048 + j];
        g[gg] = s;
    }
    float ig = 1.f / (1.f + expf(-g[0]));
    float fg = 1.f / (1.f + expf(-g[1]));
    float gt = tanhf(g[2]);
    float og = 1.f / (1.f + expf(-g[3]));
    float c = fg * cbuf[e] + ig * gt;
    float h = og * tanhf(c);
    cbuf[e] = c; hbuf[e] = h;
    if (blockIdx.x == 0) {
        if (t > 0 && threadIdx.x < 64)
            out1[threadIdx.x * TSTEPS + (t - 1)] = (float)best_idx_of_slots(slots, threadIdx.x);
        __syncthreads();
#pragma unroll
        for (int i = 0; i < 4; ++i) slots[threadIdx.x + i * 256] = 0ull;
    }
}

// Fused logits: out = h @ fcT + base; writes out0; packed atomicMax argmax.
// grid (157, 4), block 256 (4 waves). Block: 64 j x 16 b x K=512 (LDS-staged W, 2 stages).
__global__ __launch_bounds__(256) void k_logits_one(
        const float* __restrict__ hbuf, const float* __restrict__ fcT,
        const float* __restrict__ base, float* __restrict__ out0,
        u64* __restrict__ slots, int t) {
    __shared__ float wlds[256 * 64];   // 64KB: 256 kk rows x 64 j
    int jb = blockIdx.x, bh = blockIdx.y;
    int tid = threadIdx.x;
    int w = __builtin_amdgcn_readfirstlane(tid >> 6), lane = tid & 63;
    int b0 = bh * 16 + w * 4;
    int j = jb * 64 + lane;
    const float* h0 = hbuf + (size_t)b0 * 512;
    const float* h1 = h0 + 512;
    const float* h2 = h0 + 1024;
    const float* h3 = h0 + 1536;
    float a0 = 0.f, a1 = 0.f, a2 = 0.f, a3 = 0.f;
#pragma unroll
    for (int ks = 0; ks < 2; ++ks) {
        int k0 = ks * 256;
        __syncthreads();
#pragma unroll
        for (int it = 0; it < 16; ++it) {
            int f = it * 256 + tid;           // float4 index
            int r = f >> 4, cc = f & 15;
            *(float4*)&wlds[r * 64 + cc * 4] =
                *(const float4*)&fcT[(size_t)(k0 + r) * VP + jb * 64 + cc * 4];
        }
        __syncthreads();
#pragma unroll 8
        for (int kk = 0; kk < 256; ++kk) {
            float wv = wlds[kk * 64 + lane];
            int k = k0 + kk;
            a0 += h0[k] * wv; a1 += h1[k] * wv; a2 += h2[k] * wv; a3 += h3[k] * wv;
        }
    }
    // epilogue: add base, write out0, wave-argmax per b, atomicMax
    float av[4] = {a0, a1, a2, a3};
#pragma unroll
    for (int i = 0; i < 4; ++i) {
        int b = b0 + i;
        float m; int mi;
        if (j < V) {
            float val = av[i] + base[(size_t)b * VP + j];
            out0[((size_t)b * TSTEPS + t) * V + j] = val;
            m = val; mi = j;
        } else { m = -__builtin_inff(); mi = 0x7fffffff; }
#pragma unroll
        for (int mk = 1; mk < 64; mk <<= 1) {
            float ov = __shfl_xor(m, mk);
            int oi = __shfl_xor(mi, mk);
            if (ov > m || (ov == m && oi < mi)) { m = ov; mi = oi; }
        }
        if (lane == 0) atomicMax(&slots[b * SLOTSTRIDE + (jb & 7)], pack_vi(m, mi));
    }
}

// after the loop: out1[b][29]
__global__ void k_final_out1(const u64* __restrict__ slots, float* __restrict__ out1) {
    int b = threadIdx.x;
    if (b < B) out1[b * TSTEPS + (TSTEPS - 1)] = (float)best_idx_of_slots(slots, b);
}

// ---------------- launch ----------------

extern "C" void kernel_launch(void* const* d_in, const int* in_sizes, int n_in,
                              void* d_out, int out_size, void* d_ws, size_t ws_size,
                              hipStream_t stream) {
    const float* iml   = (const float*)d_in[0];
    const float* img   = (const float*)d_in[1];
    const float* m1w1  = (const float*)d_in[2];
    const float* m1b1  = (const float*)d_in[3];
    const float* m1w2  = (const float*)d_in[4];
    const float* m1b2  = (const float*)d_in[5];
    const float* m2w1  = (const float*)d_in[6];
    const float* m2b1  = (const float*)d_in[7];
    const float* m2w2  = (const float*)d_in[8];
    const float* m2b2  = (const float*)d_in[9];
    const float* wih   = (const float*)d_in[10];
    const float* whh   = (const float*)d_in[11];
    const float* bih   = (const float*)d_in[12];
    const float* bhh   = (const float*)d_in[13];
    const float* attnw = (const float*)d_in[14];
    const float* fcw   = (const float*)d_in[16];
    const float* fcb   = (const float*)d_in[17];
    const float* emb   = (const float*)d_in[18];

    float* out0 = (float*)d_out;                        // logits (B, T, V) f32
    float* out1 = out0 + (size_t)B * TSTEPS * V;        // samples (B, T) as f32

    float* ws = (float*)d_ws;
    size_t off = 0;
    float* fcT   = ws + off; off += (size_t)512 * VP;        // step-loop fcT (cols 0..512)
    float* WcT   = ws + off; off += (size_t)1024 * 2048;
    float* bigp  = ws + off; off += (size_t)8 * B * VP;      // base-path partials
    float* gpart = ws + off; off += (size_t)16 * B * 2048;   // lstm partials
    float* base  = ws + off; off += (size_t)B * VP;
    float* meanb = ws + off; off += B * 512;
    float* alpha = ws + off; off += B * KDIM;
    float* csb   = ws + off; off += B * 512;
    float* tmpb  = ws + off; off += B * 512;
    float* hbuf  = ws + off; off += B * 512;
    float* cbuf  = ws + off; off += B * 512;
    u64*   slots = (u64*)(ws + off); off += B * SLOTSTRIDE * 2;  // 64*16 u64

    // ---- precompute ----
    k_mean<<<dim3(8192), dim3(256), 0, stream>>>(iml, meanb);
    k_e_alpha<<<dim3(64), dim3(256), 0, stream>>>(iml, attnw, alpha);
    k_cs<<<dim3(8192), dim3(256), 0, stream>>>(iml, alpha, csb);
    k_dense_relu<<<dim3(2, 64), dim3(256), 0, stream>>>(meanb, m1w1, m1b1, tmpb, 512);
    k_dense_relu<<<dim3(2, 64), dim3(256), 0, stream>>>(tmpb, m1w2, m1b2, hbuf, 512);   // h0
    k_dense_relu<<<dim3(2, 64), dim3(256), 0, stream>>>(meanb, m2w1, m2b1, tmpb, 512);
    k_dense_relu<<<dim3(2, 64), dim3(256), 0, stream>>>(tmpb, m2w2, m2b2, cbuf, 512);   // c0

    // base logits from cs using transpose of fc_w cols [512,1024)
    k_transpose_fc<<<dim3(VP / 32, 16), dim3(32, 8), 0, stream>>>(fcw, fcT, 512);
    k_gemm_big<<<dim3(40, 8, 2), dim3(256), 0, stream>>>(csb, 512, fcT, VP, bigp);
    k_base_finish<<<dim3(NVC, 64), dim3(256), 0, stream>>>(bigp, fcb, base, slots);
    // overwrite fcT with transpose of fc_w cols [0,512) for the step loop
    k_transpose_fc<<<dim3(VP / 32, 16), dim3(32, 8), 0, stream>>>(fcw, fcT, 0);
    k_build_wct<<<dim3(64, 32), dim3(32, 8), 0, stream>>>(wih, whh, WcT);

    // ---- decode loop: 3 kernels/step ----
    for (int t = 0; t < TSTEPS; ++t) {
        k_lstm_gemm<<<dim3(8, 16, 2), dim3(256), 0, stream>>>(img, emb, slots, hbuf, WcT, gpart, (t == 0) ? 1 : 0);
        k_gates<<<dim3(128), dim3(256), 0, stream>>>(gpart, bih, bhh, hbuf, cbuf, slots, out1, t);
        k_logits_one<<<dim3(157, 4), dim3(256), 0, stream>>>(hbuf, fcT, base, out0, slots, t);
    }
    k_final_out1<<<dim3(1), dim3(64), 0, stream>>>(slots, out1);
}

// Round 7
// 1486.717 us; speedup vs baseline: 1.6909x; 1.6909x over previous
//
#include <hip/hip_runtime.h>
#include <hip/hip_bf16.h>

#define B 64
#define KDIM 196
#define H 512
#define V 10000
#define TSTEPS 30
#define VP 10240    // padded V for fcT / base
#define NVC 40      // VP/256 chunks
#define NSLOT 8     // argmax atomic contention-spread slots per b
#define SLOTSTRIDE 16  // u64 stride per b -> 128B, own cache line

typedef unsigned long long u64;
typedef unsigned int u32;

// pack (value, index) into sortable u64: bigger = (bigger value, then smaller index)
__device__ __forceinline__ u64 pack_vi(float v, int idx) {
    u32 kb = __float_as_uint(v);
    kb = (kb & 0x80000000u) ? ~kb : (kb | 0x80000000u);
    return ((u64)kb << 32) | (u32)(~(u32)idx);
}
__device__ __forceinline__ u32 best_idx_of_slots(const u64* __restrict__ slots, int b) {
    u64 best = slots[b * SLOTSTRIDE];
#pragma unroll
    for (int s = 1; s < NSLOT; ++s) { u64 v = slots[b * SLOTSTRIDE + s]; if (v > best) best = v; }
    return ~(u32)best;
}

// ---------------- precompute kernels ----------------

// dst[i][v] = fc_w[v][coloff + i], i in [0,512), v in [0,VP) (zero-padded)
__global__ void k_transpose_fc(const float* __restrict__ fcw, float* __restrict__ dst, int coloff) {
    __shared__ float tile[32][33];
    int v0 = blockIdx.x * 32, i0 = blockIdx.y * 32;
    int tx = threadIdx.x, ty = threadIdx.y;
#pragma unroll
    for (int r = 0; r < 32; r += 8) {
        int v = v0 + ty + r; int i = i0 + tx;
        tile[ty + r][tx] = (v < V) ? fcw[(size_t)v * 1024 + coloff + i] : 0.f;
    }
    __syncthreads();
#pragma unroll
    for (int r = 0; r < 32; r += 8) {
        int i = i0 + ty + r; int v = v0 + tx;
        dst[(size_t)i * VP + v] = tile[tx][ty + r];
    }
}

// WcT[i][j] = (i<512) ? wih[j][i] : whh[j][i-512];  i<1024, j<2048
__global__ void k_build_wct(const float* __restrict__ wih, const float* __restrict__ whh,
                            float* __restrict__ dst) {
    __shared__ float tile[32][33];
    int j0 = blockIdx.x * 32, i0 = blockIdx.y * 32;
    int tx = threadIdx.x, ty = threadIdx.y;
#pragma unroll
    for (int r = 0; r < 32; r += 8) {
        int j = j0 + ty + r; int i = i0 + tx;
        tile[ty + r][tx] = (i < 512) ? wih[(size_t)j * 512 + i] : whh[(size_t)j * 512 + i - 512];
    }
    __syncthreads();
#pragma unroll
    for (int r = 0; r < 32; r += 8) {
        int i = i0 + ty + r; int j = j0 + tx;
        dst[(size_t)i * 2048 + j] = tile[tx][ty + r];
    }
}

// mean over K per (b,h) row; one wave per row
__global__ void k_mean(const float* __restrict__ iml, float* __restrict__ mean) {
    int w = threadIdx.x >> 6, lane = threadIdx.x & 63;
    int row = blockIdx.x * 4 + w;
    const float* p = iml + (size_t)row * KDIM;
    float s = p[lane] + p[lane + 64] + p[lane + 128] + ((lane < 4) ? p[lane + 192] : 0.f);
#pragma unroll
    for (int off = 32; off; off >>= 1) s += __shfl_down(s, off);
    if (lane == 0) mean[row] = s * (1.f / 196.f);
}

// alpha[b][k] = softmax_k( sum_h iml[b][h][k] * attn_w[h] )
__global__ void k_e_alpha(const float* __restrict__ iml, const float* __restrict__ attn_w,
                          float* __restrict__ alpha) {
    int b = blockIdx.x, t = threadIdx.x;
    __shared__ float wa[512];
    wa[t] = attn_w[t]; wa[t + 256] = attn_w[t + 256];
    __syncthreads();
    float acc = 0.f;
    if (t < KDIM) {
        const float* p = iml + (size_t)b * 512 * KDIM + t;
#pragma unroll 8
        for (int h = 0; h < 512; ++h) acc += p[(size_t)h * KDIM] * wa[h];
    }
    __shared__ float red[256];
    red[t] = (t < KDIM) ? acc : -__builtin_inff();
    __syncthreads();
    for (int s = 128; s; s >>= 1) { if (t < s) red[t] = fmaxf(red[t], red[t + s]); __syncthreads(); }
    float mx = red[0];
    __syncthreads();
    float ex = (t < KDIM) ? expf(acc - mx) : 0.f;
    red[t] = ex; __syncthreads();
    for (int s = 128; s; s >>= 1) { if (t < s) red[t] += red[t + s]; __syncthreads(); }
    if (t < KDIM) alpha[b * KDIM + t] = ex / red[0];
}

// cs[b][h] = sum_k alpha[b][k] * iml[b][h][k]; one wave per row
__global__ void k_cs(const float* __restrict__ iml, const float* __restrict__ alpha,
                     float* __restrict__ cs) {
    int w = threadIdx.x >> 6, lane = threadIdx.x & 63;
    int row = blockIdx.x * 4 + w;
    int b = row >> 9;
    const float* p = iml + (size_t)row * KDIM;
    const float* al = alpha + b * KDIM;
    float s = p[lane] * al[lane] + p[lane + 64] * al[lane + 64] + p[lane + 128] * al[lane + 128]
            + ((lane < 4) ? p[lane + 192] * al[lane + 192] : 0.f);
#pragma unroll
    for (int off = 32; off; off >>= 1) s += __shfl_down(s, off);
    if (lane == 0) cs[row] = s;
}

// out[b*ostride + j] = relu(bias[j] + sum_i in[b][i] * W[j][i])
__global__ void k_dense_relu(const float* __restrict__ in, const float* __restrict__ W,
                             const float* __restrict__ bias, float* __restrict__ out, int ostride) {
    int b = blockIdx.y; int j = blockIdx.x * 256 + threadIdx.x;
    __shared__ float xs[512];
    xs[threadIdx.x] = in[b * 512 + threadIdx.x];
    xs[threadIdx.x + 256] = in[b * 512 + threadIdx.x + 256];
    __syncthreads();
    float acc = bias[j];
    const float4* w4 = (const float4*)(W + (size_t)j * 512);
#pragma unroll 4
    for (int i4 = 0; i4 < 128; ++i4) {
        float4 w = w4[i4];
        float4 x = *(const float4*)&xs[i4 * 4];
        acc += w.x * x.x + w.y * x.y + w.z * x.z + w.w * x.w;
    }
    out[(size_t)b * ostride + j] = fmaxf(acc, 0.f);
}

// split-K GEMM for the one-time base-logits (cs @ fcT_hi); grid (40,8,2)
__global__ void k_gemm_big(const float* __restrict__ A, int astride,
                           const float* __restrict__ Wt, int wn,
                           float* __restrict__ part) {
    int jb = blockIdx.x, kc = blockIdx.y, bh = blockIdx.z;
    int w = threadIdx.x >> 6, lane = threadIdx.x & 63;
    int b0 = __builtin_amdgcn_readfirstlane(bh * 32 + w * 8);
    int k0 = kc * 64;
    int j0 = jb * 256 + lane * 4;
    float4 acc[8];
#pragma unroll
    for (int b = 0; b < 8; ++b) acc[b] = make_float4(0.f, 0.f, 0.f, 0.f);
    const float* wp = Wt + (size_t)k0 * wn + j0;
    const float* xp = A + (size_t)b0 * astride + k0;
#pragma unroll 8
    for (int kk = 0; kk < 64; ++kk) {
        float4 w4 = *(const float4*)(wp + (size_t)kk * wn);
#pragma unroll
        for (int b = 0; b < 8; ++b) {
            float xv = xp[(size_t)b * astride + kk];
            acc[b].x += xv * w4.x; acc[b].y += xv * w4.y;
            acc[b].z += xv * w4.z; acc[b].w += xv * w4.w;
        }
    }
#pragma unroll
    for (int b = 0; b < 8; ++b)
        *(float4*)(part + (size_t)(kc * 64 + b0 + b) * wn + j0) = acc[b];
}

// base[b][v] = sum of 8 partials + fc_b[v]; block(0,0) also zeroes argmax slots
__global__ void k_base_finish(const float* __restrict__ lpart, const float* __restrict__ fc_b,
                              float* __restrict__ base, u64* __restrict__ slots) {
    int b = blockIdx.y; int v = blockIdx.x * 256 + threadIdx.x;
    if (v < V) {
        float s = fc_b[v];
#pragma unroll
        for (int c = 0; c < 8; ++c) s += lpart[(size_t)(c * 64 + b) * VP + v];
        base[(size_t)b * VP + v] = s;
    }
    if (blockIdx.x == 0 && blockIdx.y == 0) {
#pragma unroll
        for (int i = 0; i < 4; ++i) slots[threadIdx.x + i * 256] = 0ull;
    }
}

// ---------------- per-step kernels ----------------

// LSTM gates GEMM, split-K 16 (K=64 each). x = t0 ? img : emb[argmax(slots)].
// grid (8, 16, 4), 256 thr; wave = 4 b x 256 j. part[(kc*64+b)*2048 + j]
__global__ void k_lstm_gemm(const float* __restrict__ img, const float* __restrict__ emb,
                            const u64* __restrict__ slots, const float* __restrict__ hbuf,
                            const float* __restrict__ WcT, float* __restrict__ part, int t0) {
    int jb = blockIdx.x, kc = blockIdx.y, bh = blockIdx.z;
    int w = threadIdx.x >> 6, lane = threadIdx.x & 63;
    int b0 = __builtin_amdgcn_readfirstlane(bh * 16 + w * 4);
    int k0 = kc * 64;
    int j0 = jb * 256 + lane * 4;
    const float* xr[4];
    if (k0 < 512) {
        if (t0) {
#pragma unroll
            for (int i = 0; i < 4; ++i) xr[i] = img + (size_t)(b0 + i) * 512 + k0;
        } else {
#pragma unroll
            for (int i = 0; i < 4; ++i) {
                u32 idx = best_idx_of_slots(slots, b0 + i);
                xr[i] = emb + (size_t)idx * 512 + k0;
            }
        }
    } else {
#pragma unroll
        for (int i = 0; i < 4; ++i) xr[i] = hbuf + (size_t)(b0 + i) * 512 + (k0 - 512);
    }
    float4 acc[4];
#pragma unroll
    for (int i = 0; i < 4; ++i) acc[i] = make_float4(0.f, 0.f, 0.f, 0.f);
    const float* wp = WcT + (size_t)k0 * 2048 + j0;
#pragma unroll 8
    for (int kk = 0; kk < 64; ++kk) {
        float4 w4 = *(const float4*)(wp + (size_t)kk * 2048);
#pragma unroll
        for (int i = 0; i < 4; ++i) {
            float xv = xr[i][kk];
            acc[i].x += xv * w4.x; acc[i].y += xv * w4.y;
            acc[i].z += xv * w4.z; acc[i].w += xv * w4.w;
        }
    }
#pragma unroll
    for (int i = 0; i < 4; ++i)
        *(float4*)(part + (size_t)(kc * 64 + b0 + i) * 2048 + j0) = acc[i];
}

// reduce 16 partials + biases + gates; h -> hbuf, c in place.
// block 0: out1[b][t-1] from slots, then zero slots (before logits_finish refills).
__global__ void k_gates(const float* __restrict__ part, const float* __restrict__ bih,
                        const float* __restrict__ bhh, float* __restrict__ hbuf,
                        float* __restrict__ cbuf, u64* __restrict__ slots,
                        float* __restrict__ out1, int t) {
    int e = blockIdx.x * 256 + threadIdx.x;
    int b = e >> 9, jj = e & 511;
    float g[4];
#pragma unroll
    for (int gg = 0; gg < 4; ++gg) {
        int j = jj + gg * 512;
        float s = bih[j] + bhh[j];
#pragma unroll
        for (int c = 0; c < 16; ++c) s += part[(size_t)(c * 64 + b) * 2048 + j];
        g[gg] = s;
    }
    float ig = 1.f / (1.f + expf(-g[0]));
    float fg = 1.f / (1.f + expf(-g[1]));
    float gt = tanhf(g[2]);
    float og = 1.f / (1.f + expf(-g[3]));
    float c = fg * cbuf[e] + ig * gt;
    float h = og * tanhf(c);
    cbuf[e] = c; hbuf[e] = h;
    if (blockIdx.x == 0) {
        if (t > 0 && threadIdx.x < 64)
            out1[threadIdx.x * TSTEPS + (t - 1)] = (float)best_idx_of_slots(slots, threadIdx.x);
        __syncthreads();
#pragma unroll
        for (int i = 0; i < 4; ++i) slots[threadIdx.x + i * 256] = 0ull;
    }
}

// logits split-K GEMM: part[(kc*64+b)*VP + j] = sum_{K=128 chunk} h[b][k] * fcT[k][j]
// grid (40, 4, 2), 256 thr; wave = 8 b x 256 j. 40 % 8 == 0 -> same-jb blocks share an XCD.
__global__ void k_logits_gemm(const float* __restrict__ hbuf, const float* __restrict__ fcT,
                              float* __restrict__ part) {
    int jb = blockIdx.x, kc = blockIdx.y, bh = blockIdx.z;
    int w = threadIdx.x >> 6, lane = threadIdx.x & 63;
    int b0 = __builtin_amdgcn_readfirstlane(bh * 32 + w * 8);
    int k0 = kc * 128;
    int j0 = jb * 256 + lane * 4;
    float4 acc[8];
#pragma unroll
    for (int b = 0; b < 8; ++b) acc[b] = make_float4(0.f, 0.f, 0.f, 0.f);
    const float* wp = fcT + (size_t)k0 * VP + j0;
    const float* xp = hbuf + (size_t)b0 * 512 + k0;
#pragma unroll 8
    for (int kk = 0; kk < 128; ++kk) {
        float4 w4 = *(const float4*)(wp + (size_t)kk * VP);
#pragma unroll
        for (int b = 0; b < 8; ++b) {
            float xv = xp[(size_t)b * 512 + kk];
            acc[b].x += xv * w4.x; acc[b].y += xv * w4.y;
            acc[b].z += xv * w4.z; acc[b].w += xv * w4.w;
        }
    }
#pragma unroll
    for (int b = 0; b < 8; ++b)
        *(float4*)(part + (size_t)(kc * 64 + b0 + b) * VP + j0) = acc[b];
}

// reduce 4 partials + base; write out0; wave-argmax -> slots atomicMax.
// grid (40, 64), 256 thr.
__global__ void k_logits_finish(const float* __restrict__ lpart, const float* __restrict__ base,
                                float* __restrict__ out0, u64* __restrict__ slots, int t) {
    int b = blockIdx.y, vc = blockIdx.x, tid = threadIdx.x;
    int lane = tid & 63;
    int v = vc * 256 + tid;
    float val = -__builtin_inff();
    if (v < V) {
        float s = base[(size_t)b * VP + v];
#pragma unroll
        for (int c = 0; c < 4; ++c) s += lpart[(size_t)(c * 64 + b) * VP + v];
        out0[((size_t)b * TSTEPS + t) * V + v] = s;
        val = s;
    }
    float m = val; int mi = (v < V) ? v : 0x7fffffff;
#pragma unroll
    for (int mk = 1; mk < 64; mk <<= 1) {
        float ov = __shfl_xor(m, mk);
        int oi = __shfl_xor(mi, mk);
        if (ov > m || (ov == m && oi < mi)) { m = ov; mi = oi; }
    }
    if (lane == 0) atomicMax(&slots[b * SLOTSTRIDE + (vc & 7)], pack_vi(m, mi));
}

// after the loop: out1[b][29]
__global__ void k_final_out1(const u64* __restrict__ slots, float* __restrict__ out1) {
    int b = threadIdx.x;
    if (b < B) out1[b * TSTEPS + (TSTEPS - 1)] = (float)best_idx_of_slots(slots, b);
}

// ---------------- launch ----------------

extern "C" void kernel_launch(void* const* d_in, const int* in_sizes, int n_in,
                              void* d_out, int out_size, void* d_ws, size_t ws_size,
                              hipStream_t stream) {
    const float* iml   = (const float*)d_in[0];
    const float* img   = (const float*)d_in[1];
    const float* m1w1  = (const float*)d_in[2];
    const float* m1b1  = (const float*)d_in[3];
    const float* m1w2  = (const float*)d_in[4];
    const float* m1b2  = (const float*)d_in[5];
    const float* m2w1  = (const float*)d_in[6];
    const float* m2b1  = (const float*)d_in[7];
    const float* m2w2  = (const float*)d_in[8];
    const float* m2b2  = (const float*)d_in[9];
    const float* wih   = (const float*)d_in[10];
    const float* whh   = (const float*)d_in[11];
    const float* bih   = (const float*)d_in[12];
    const float* bhh   = (const float*)d_in[13];
    const float* attnw = (const float*)d_in[14];
    const float* fcw   = (const float*)d_in[16];
    const float* fcb   = (const float*)d_in[17];
    const float* emb   = (const float*)d_in[18];

    float* out0 = (float*)d_out;                        // logits (B, T, V) f32
    float* out1 = out0 + (size_t)B * TSTEPS * V;        // samples (B, T) as f32

    float* ws = (float*)d_ws;
    size_t off = 0;
    float* fcT   = ws + off; off += (size_t)512 * VP;        // step-loop fcT (cols 0..512)
    float* WcT   = ws + off; off += (size_t)1024 * 2048;
    float* bigp  = ws + off; off += (size_t)8 * B * VP;      // base-path + logits partials
    float* gpart = ws + off; off += (size_t)16 * B * 2048;   // lstm partials
    float* base  = ws + off; off += (size_t)B * VP;
    float* meanb = ws + off; off += B * 512;
    float* alpha = ws + off; off += B * KDIM;
    float* csb   = ws + off; off += B * 512;
    float* tmpb  = ws + off; off += B * 512;
    float* hbuf  = ws + off; off += B * 512;
    float* cbuf  = ws + off; off += B * 512;
    u64*   slots = (u64*)(ws + off); off += B * SLOTSTRIDE * 2;

    // ---- precompute ----
    k_mean<<<dim3(8192), dim3(256), 0, stream>>>(iml, meanb);
    k_e_alpha<<<dim3(64), dim3(256), 0, stream>>>(iml, attnw, alpha);
    k_cs<<<dim3(8192), dim3(256), 0, stream>>>(iml, alpha, csb);
    k_dense_relu<<<dim3(2, 64), dim3(256), 0, stream>>>(meanb, m1w1, m1b1, tmpb, 512);
    k_dense_relu<<<dim3(2, 64), dim3(256), 0, stream>>>(tmpb, m1w2, m1b2, hbuf, 512);   // h0
    k_dense_relu<<<dim3(2, 64), dim3(256), 0, stream>>>(meanb, m2w1, m2b1, tmpb, 512);
    k_dense_relu<<<dim3(2, 64), dim3(256), 0, stream>>>(tmpb, m2w2, m2b2, cbuf, 512);   // c0

    // base logits from cs using transpose of fc_w cols [512,1024)
    k_transpose_fc<<<dim3(VP / 32, 16), dim3(32, 8), 0, stream>>>(fcw, fcT, 512);
    k_gemm_big<<<dim3(40, 8, 2), dim3(256), 0, stream>>>(csb, 512, fcT, VP, bigp);
    k_base_finish<<<dim3(NVC, 64), dim3(256), 0, stream>>>(bigp, fcb, base, slots);
    // overwrite fcT with transpose of fc_w cols [0,512) for the step loop
    k_transpose_fc<<<dim3(VP / 32, 16), dim3(32, 8), 0, stream>>>(fcw, fcT, 0);
    k_build_wct<<<dim3(64, 32), dim3(32, 8), 0, stream>>>(wih, whh, WcT);

    // ---- decode loop: 4 kernels/step ----
    for (int t = 0; t < TSTEPS; ++t) {
        k_lstm_gemm<<<dim3(8, 16, 4), dim3(256), 0, stream>>>(img, emb, slots, hbuf, WcT, gpart, (t == 0) ? 1 : 0);
        k_gates<<<dim3(128), dim3(256), 0, stream>>>(gpart, bih, bhh, hbuf, cbuf, slots, out1, t);
        k_logits_gemm<<<dim3(40, 4, 2), dim3(256), 0, stream>>>(hbuf, fcT, bigp);
        k_logits_finish<<<dim3(40, 64), dim3(256), 0, stream>>>(bigp, base, out0, slots, t);
    }
    k_final_out1<<<dim3(1), dim3(64), 0, stream>>>(slots, out1);
}